// Round 11
// baseline (420.017 us; speedup 1.0000x reference)
//
#include <hip/hip_runtime.h>
#include <hip/hip_bf16.h>
#include <stdint.h>

// Problem constants: B=8, S=2048, D_IN=4096, D_OUT=4096
#define MROWS 16384
#define DIN   4096
#define DOUT  4096
#define KEFF  1024

typedef __attribute__((ext_vector_type(8))) __bf16 bf16x8;
typedef __attribute__((ext_vector_type(4))) float f32x4;

#define AS1 __attribute__((address_space(1)))
#define AS3 __attribute__((address_space(3)))

__device__ __forceinline__ uint32_t f2bf_rne(float f) {
  union { float f; uint32_t u; } v; v.f = f;
  uint32_t u = v.u;
  return (u + 0x7fffu + ((u >> 16) & 1u)) >> 16;
}

// ---- fused persistent kernel: distributed gather -> grid sync -> R4 GEMM ----
#define BM 256
#define BN 256
#define BK 64
#define NT (KEFF / BK)   // 16
#define TPB 4            // output tiles per block; grid = 64*4 = 256

// LDS k-half: [128 superrows][128B]; superrow sr = rows 2sr,2sr+1 (32 k = 64B
// each), 8x16B slots XOR-swizzled by (sr&7).
__device__ __forceinline__ int swz_off(int R, int lg) {
  int sr = R >> 1;
  return sr * 128 + (((((R & 1) << 2) | lg) ^ (sr & 7)) << 4);
}

#define WAIT_VM(n) asm volatile("s_waitcnt vmcnt(" #n ")" ::: "memory")
#define BAR() __builtin_amdgcn_s_barrier()

__global__ __launch_bounds__(512, 2) void venom_fused(
    const float* __restrict__ x, const float* __restrict__ w,
    const float* __restrict__ bias, float* __restrict__ C,
    uint32_t* __restrict__ xgw, uint32_t* __restrict__ wgw,
    uint32_t* __restrict__ ctr) {
  __shared__ __bf16 As[2][2][128 * 64];
  __shared__ __bf16 Bs[2][2][128 * 64];

  const int t = threadIdx.x;
  const int bid = blockIdx.x;

  // ---------------- Phase 1: distributed gather (disjoint slices) -----------
  {
    const int PX = MROWS * (DIN / 16);  // 4,194,304 pairs (uint2 each)
    const int PW = DOUT * (DIN / 16);   // 1,048,576
    const int xpb = PX / 256;           // 16384 pairs per block
    const int wpb = PW / 256;           // 4096
    uint2* xg2 = (uint2*)xgw;
    uint2* wg2 = (uint2*)wgw;
    #pragma unroll 4
    for (int i = t; i < xpb; i += 512) {
      int idx = bid * xpb + i;
      const float4* p = reinterpret_cast<const float4*>(x) + (size_t)idx * 4;
      float4 a = p[0], b = p[2];
      uint2 r;
      r.x = f2bf_rne(a.x) | (f2bf_rne(a.z) << 16);
      r.y = f2bf_rne(b.x) | (f2bf_rne(b.z) << 16);
      xg2[idx] = r;
    }
    #pragma unroll 4
    for (int i = t; i < wpb; i += 512) {
      int idx = bid * wpb + i;
      const float4* p = reinterpret_cast<const float4*>(w) + (size_t)idx * 4;
      float4 a = p[0], b = p[2];
      uint2 r;
      r.x = f2bf_rne(a.x) | (f2bf_rne(a.z) << 16);
      r.y = f2bf_rne(b.x) | (f2bf_rne(b.z) << 16);
      wg2[idx] = r;
    }
  }

  // ---------------- Phase 2: device-scope grid sync -------------------------
  WAIT_VM(0);          // drain this thread's gather loads/stores
  __threadfence();     // make block's stores device-visible
  __syncthreads();     // all threads of block drained
  if (t == 0) {
    __hip_atomic_fetch_add(ctr, 1u, __ATOMIC_ACQ_REL, __HIP_MEMORY_SCOPE_AGENT);
    while (__hip_atomic_load(ctr, __ATOMIC_ACQUIRE, __HIP_MEMORY_SCOPE_AGENT) <
           (uint32_t)gridDim.x)
      __builtin_amdgcn_s_sleep(8);
  }
  __syncthreads();

  // ---------------- Phase 3: R4 GEMM (verbatim structure) -------------------
  const __bf16* A  = (const __bf16*)xgw;
  const __bf16* Bm = (const __bf16*)wgw;

  // XCD-bijective swizzle (grid=256)
  int nwg = gridDim.x;
  int cpx = nwg >> 3;
  int swz = (bid & 7) * cpx + (bid >> 3);
  int mblk = swz >> 2;   // 0..63
  int ngrp = swz & 3;    // tile j covers nblk = ngrp*TPB + j

  int wid = t >> 6, l = t & 63;
  int wr = wid >> 2, wc = wid & 3;   // 2x4 wave grid; wave owns 128x64 of C
  int lr = l & 15, lg = l >> 4;

  const __bf16* Ag = A + (size_t)(mblk * BM) * KEFF;

  float biasr[TPB][4];
  #pragma unroll
  for (int j = 0; j < TPB; ++j)
    #pragma unroll
    for (int ni = 0; ni < 4; ++ni)
      biasr[j][ni] = bias[(ngrp * TPB + j) * BN + wc * 64 + ni * 16 + lr];

  f32x4 acc[8][4] = {};

  auto stage_half = [&](int j2, int kt2, int kh) {
    const int buf = kt2 & 1;
    const __bf16* Bg = Bm + (size_t)((ngrp * TPB + j2) * BN) * KEFF;
    const int k0 = kt2 * BK + kh * 32;
    #pragma unroll
    for (int i = 0; i < 2; ++i) {
      int e = i * 512 + t;
      int sr = e >> 3;
      int s = (e & 7) ^ (sr & 7);
      int row = sr * 2 + (s >> 2);
      int koff = (s & 3) * 8;
      __builtin_amdgcn_global_load_lds(
          (const AS1 uint32_t*)(Ag + (size_t)row * KEFF + k0 + koff),
          ((AS3 uint32_t*)&As[buf][kh][0]) + e * 4, 16, 0, 0);
      __builtin_amdgcn_global_load_lds(
          (const AS1 uint32_t*)(Bg + (size_t)row * KEFF + k0 + koff),
          ((AS3 uint32_t*)&Bs[buf][kh][0]) + e * 4, 16, 0, 0);
    }
  };

  // Prologue: both halves of (0,0); keep newest 4 loads in flight.
  stage_half(0, 0, 0);
  stage_half(0, 0, 1);
  WAIT_VM(4);
  BAR();

  bf16x8 bfrag[4];

  #pragma unroll
  for (int j = 0; j < TPB; ++j) {
    #pragma unroll 1
    for (int kt = 0; kt < NT; ++kt) {
      const int cur = kt & 1;
      const bool last_it = (j == TPB - 1) && (kt == NT - 1);
      const int j2  = (kt < NT - 1) ? j : j + 1;
      const int kt2 = (kt < NT - 1) ? kt + 1 : 0;

      #pragma unroll
      for (int ph = 0; ph < 4; ++ph) {
        const int mh = ph & 1, kh = ph >> 1;
        const char* aB = (const char*)&As[cur][kh][0];
        bf16x8 af[4];
        #pragma unroll
        for (int mi = 0; mi < 4; ++mi)
          af[mi] = *(const bf16x8*)(aB + swz_off(wr * 128 + mh * 64 + mi * 16 + lr, lg));
        if (mh == 0) {
          const char* bB = (const char*)&Bs[cur][kh][0];
          #pragma unroll
          for (int ni = 0; ni < 4; ++ni)
            bfrag[ni] = *(const bf16x8*)(bB + swz_off(wc * 64 + ni * 16 + lr, lg));
          if (!last_it) stage_half(j2, kt2, kh);
        }

        BAR();
        __builtin_amdgcn_s_setprio(1);
        #pragma unroll
        for (int mi = 0; mi < 4; ++mi)
          #pragma unroll
          for (int ni = 0; ni < 4; ++ni)
            acc[mh * 4 + mi][ni] = __builtin_amdgcn_mfma_f32_16x16x32_bf16(
                af[mi], bfrag[ni], acc[mh * 4 + mi][ni], 0, 0, 0);
        __builtin_amdgcn_s_setprio(0);

        if (ph == 1) {
          if (!last_it) WAIT_VM(4);
          else          WAIT_VM(0);
          BAR();
        } else if (ph == 3) {
          if (!last_it) {
            WAIT_VM(4);
            BAR();
          }
        } else {
          BAR();
        }
      }
    }

    // Epilogue for tile j (static biasr index; registers/stores only).
    {
      int colbase = (ngrp * TPB + j) * BN + wc * 64;
      int rowbase = mblk * BM + wr * 128;
      #pragma unroll
      for (int mh = 0; mh < 2; ++mh)
        #pragma unroll
        for (int mi = 0; mi < 4; ++mi) {
          int row0 = rowbase + mh * 64 + mi * 16 + lg * 4;
          #pragma unroll
          for (int ni = 0; ni < 4; ++ni) {
            int col = colbase + ni * 16 + lr;
            f32x4 cv = acc[mh * 4 + mi][ni];
            #pragma unroll
            for (int jj = 0; jj < 4; ++jj)
              C[(size_t)(row0 + jj) * DOUT + col] = cv[jj] + biasr[j][ni];
          }
        }
      #pragma unroll
      for (int q = 0; q < 8; ++q)
        #pragma unroll
        for (int ni = 0; ni < 4; ++ni)
          acc[q][ni] = (f32x4){0.f, 0.f, 0.f, 0.f};
    }
  }
}

// Correct-but-slow fallback if workspace is too small (should not trigger).
__global__ void venom_naive(const float* __restrict__ x, const float* __restrict__ w,
                            const float* __restrict__ bias, float* __restrict__ out) {
  size_t total = (size_t)MROWS * DOUT;
  size_t stride = (size_t)gridDim.x * blockDim.x;
  for (size_t idx = (size_t)blockIdx.x * blockDim.x + threadIdx.x; idx < total;
       idx += stride) {
    int m = (int)(idx / DOUT), n = (int)(idx % DOUT);
    const float* xr = x + (size_t)m * DIN;
    const float* wr = w + (size_t)n * DIN;
    float s = 0.f;
    for (int g = 0; g < DIN / 8; ++g)
      s += xr[g * 8] * wr[g * 8] + xr[g * 8 + 2] * wr[g * 8 + 2];
    out[idx] = s + bias[n];
  }
}

extern "C" void kernel_launch(void* const* d_in, const int* in_sizes, int n_in,
                              void* d_out, int out_size, void* d_ws, size_t ws_size,
                              hipStream_t stream) {
  const float* x    = (const float*)d_in[0];
  const float* wgt  = (const float*)d_in[1];
  const float* bias = (const float*)d_in[2];
  float* out = (float*)d_out;

  const size_t xg_bytes = (size_t)MROWS * KEFF * 2;  // 33.5 MB
  const size_t wg_bytes = (size_t)DOUT * KEFF * 2;   //  8.4 MB
  const size_t ctr_off  = xg_bytes + wg_bytes;

  if (ws_size < ctr_off + 128) {
    venom_naive<<<2048, 256, 0, stream>>>(x, wgt, bias, out);
    return;
  }

  uint32_t* xg  = (uint32_t*)d_ws;
  uint32_t* wg  = (uint32_t*)((char*)d_ws + xg_bytes);
  uint32_t* ctr = (uint32_t*)((char*)d_ws + ctr_off);

  // Reset the grid-sync counter every launch (graph-capture-safe).
  hipMemsetAsync(ctr, 0, sizeof(uint32_t), stream);

  // 256 blocks = 1 per CU (128 KiB LDS), all co-resident -> spin-sync is safe.
  venom_fused<<<256, 512, 0, stream>>>(x, wgt, bias, out, xg, wg, ctr);
}

// Round 12
// 329.137 us; speedup vs baseline: 1.2761x; 1.2761x over previous
//
#include <hip/hip_runtime.h>
#include <hip/hip_bf16.h>
#include <stdint.h>

// Problem constants: B=8, S=2048, D_IN=4096, D_OUT=4096
#define MROWS 16384
#define DIN   4096
#define DOUT  4096
#define KEFF  1024

typedef __attribute__((ext_vector_type(8))) __bf16 bf16x8;
typedef __attribute__((ext_vector_type(4))) float f32x4;

#define AS1 __attribute__((address_space(1)))
#define AS3 __attribute__((address_space(3)))

__device__ __forceinline__ uint32_t f2bf_rne(float f) {
  union { float f; uint32_t u; } v; v.f = f;
  uint32_t u = v.u;
  return (u + 0x7fffu + ((u >> 16) & 1u)) >> 16;
}

// ---- fused persistent kernel: batched gather -> grid sync -> R4 GEMM ----
#define BM 256
#define BN 256
#define BK 64
#define NT (KEFF / BK)   // 16
#define TPB 4            // output tiles per block; grid = 64*4 = 256

// LDS k-half: [128 superrows][128B]; superrow sr = rows 2sr,2sr+1 (32 k = 64B
// each), 8x16B slots XOR-swizzled by (sr&7).
__device__ __forceinline__ int swz_off(int R, int lg) {
  int sr = R >> 1;
  return sr * 128 + (((((R & 1) << 2) | lg) ^ (sr & 7)) << 4);
}

#define WAIT_VM(n) asm volatile("s_waitcnt vmcnt(" #n ")" ::: "memory")
#define BAR() __builtin_amdgcn_s_barrier()

__global__ __launch_bounds__(512, 2) void venom_fused2(
    const float* __restrict__ x, const float* __restrict__ w,
    const float* __restrict__ bias, float* __restrict__ C,
    uint32_t* __restrict__ xgw, uint32_t* __restrict__ wgw,
    uint32_t* __restrict__ ctr) {
  __shared__ __bf16 As[2][2][128 * 64];
  __shared__ __bf16 Bs[2][2][128 * 64];

  const int t = threadIdx.x;
  const int bid = blockIdx.x;

  // ---- Phase 1: distributed gather, 8-pair batches (16 loads in flight) ----
  {
    const int PX = MROWS * (DIN / 16);  // 4,194,304 pairs
    const int PW = DOUT * (DIN / 16);   // 1,048,576
    const int xpb = PX / 256;           // 16384 pairs per block
    const int wpb = PW / 256;           // 4096
    uint2* xg2 = (uint2*)xgw;
    uint2* wg2 = (uint2*)wgw;
    const float4* px = reinterpret_cast<const float4*>(x);
    const float4* pw = reinterpret_cast<const float4*>(w);

    int xbase = bid * xpb;
    #pragma unroll 1
    for (int b0 = 0; b0 < xpb; b0 += 512 * 8) {
      float4 va[8], vb[8];
      #pragma unroll
      for (int u = 0; u < 8; ++u) {
        int idx = xbase + b0 + u * 512 + t;
        va[u] = px[(size_t)idx * 4];
        vb[u] = px[(size_t)idx * 4 + 2];
      }
      #pragma unroll
      for (int u = 0; u < 8; ++u) {
        int idx = xbase + b0 + u * 512 + t;
        uint2 r;
        r.x = f2bf_rne(va[u].x) | (f2bf_rne(va[u].z) << 16);
        r.y = f2bf_rne(vb[u].x) | (f2bf_rne(vb[u].z) << 16);
        xg2[idx] = r;
      }
    }
    int wbase = bid * wpb;
    {
      float4 va[8], vb[8];
      #pragma unroll
      for (int u = 0; u < 8; ++u) {
        int idx = wbase + u * 512 + t;
        va[u] = pw[(size_t)idx * 4];
        vb[u] = pw[(size_t)idx * 4 + 2];
      }
      #pragma unroll
      for (int u = 0; u < 8; ++u) {
        int idx = wbase + u * 512 + t;
        uint2 r;
        r.x = f2bf_rne(va[u].x) | (f2bf_rne(va[u].z) << 16);
        r.y = f2bf_rne(vb[u].x) | (f2bf_rne(vb[u].z) << 16);
        wg2[idx] = r;
      }
    }
  }

  // ---- Phase 2: device-scope grid sync (fences from t0 only) ----
  WAIT_VM(0);          // this thread's loads/stores complete at L2
  __syncthreads();     // whole block drained
  if (t == 0) {
    // ACQ_REL RMW: release side writes back this XCD's L2 before the add.
    __hip_atomic_fetch_add(ctr, 1u, __ATOMIC_ACQ_REL, __HIP_MEMORY_SCOPE_AGENT);
    // Relaxed polling (no per-poll cache invalidate; agent atomics bypass L2).
    while (__hip_atomic_load(ctr, __ATOMIC_RELAXED, __HIP_MEMORY_SCOPE_AGENT) <
           (uint32_t)gridDim.x)
      __builtin_amdgcn_s_sleep(8);
    // One acquire: invalidate L1/L2 so we see all XCDs' gathered data.
    (void)__hip_atomic_load(ctr, __ATOMIC_ACQUIRE, __HIP_MEMORY_SCOPE_AGENT);
  }
  __syncthreads();

  // ---- Phase 3: R4 GEMM (verbatim structure) ----
  const __bf16* A  = (const __bf16*)xgw;
  const __bf16* Bm = (const __bf16*)wgw;

  int nwg = gridDim.x;
  int cpx = nwg >> 3;
  int swz = (bid & 7) * cpx + (bid >> 3);
  int mblk = swz >> 2;   // 0..63
  int ngrp = swz & 3;    // tile j covers nblk = ngrp*TPB + j

  int wid = t >> 6, l = t & 63;
  int wr = wid >> 2, wc = wid & 3;   // 2x4 wave grid; wave owns 128x64 of C
  int lr = l & 15, lg = l >> 4;

  const __bf16* Ag = A + (size_t)(mblk * BM) * KEFF;

  float biasr[TPB][4];
  #pragma unroll
  for (int j = 0; j < TPB; ++j)
    #pragma unroll
    for (int ni = 0; ni < 4; ++ni)
      biasr[j][ni] = bias[(ngrp * TPB + j) * BN + wc * 64 + ni * 16 + lr];

  f32x4 acc[8][4] = {};

  auto stage_half = [&](int j2, int kt2, int kh) {
    const int buf = kt2 & 1;
    const __bf16* Bg = Bm + (size_t)((ngrp * TPB + j2) * BN) * KEFF;
    const int k0 = kt2 * BK + kh * 32;
    #pragma unroll
    for (int i = 0; i < 2; ++i) {
      int e = i * 512 + t;
      int sr = e >> 3;
      int s = (e & 7) ^ (sr & 7);
      int row = sr * 2 + (s >> 2);
      int koff = (s & 3) * 8;
      __builtin_amdgcn_global_load_lds(
          (const AS1 uint32_t*)(Ag + (size_t)row * KEFF + k0 + koff),
          ((AS3 uint32_t*)&As[buf][kh][0]) + e * 4, 16, 0, 0);
      __builtin_amdgcn_global_load_lds(
          (const AS1 uint32_t*)(Bg + (size_t)row * KEFF + k0 + koff),
          ((AS3 uint32_t*)&Bs[buf][kh][0]) + e * 4, 16, 0, 0);
    }
  };

  // Prologue: both halves of (0,0); keep newest 4 loads in flight.
  stage_half(0, 0, 0);
  stage_half(0, 0, 1);
  WAIT_VM(4);
  BAR();

  bf16x8 bfrag[4];

  #pragma unroll
  for (int j = 0; j < TPB; ++j) {
    #pragma unroll 1
    for (int kt = 0; kt < NT; ++kt) {
      const int cur = kt & 1;
      const bool last_it = (j == TPB - 1) && (kt == NT - 1);
      const int j2  = (kt < NT - 1) ? j : j + 1;
      const int kt2 = (kt < NT - 1) ? kt + 1 : 0;

      #pragma unroll
      for (int ph = 0; ph < 4; ++ph) {
        const int mh = ph & 1, kh = ph >> 1;
        const char* aB = (const char*)&As[cur][kh][0];
        bf16x8 af[4];
        #pragma unroll
        for (int mi = 0; mi < 4; ++mi)
          af[mi] = *(const bf16x8*)(aB + swz_off(wr * 128 + mh * 64 + mi * 16 + lr, lg));
        if (mh == 0) {
          const char* bB = (const char*)&Bs[cur][kh][0];
          #pragma unroll
          for (int ni = 0; ni < 4; ++ni)
            bfrag[ni] = *(const bf16x8*)(bB + swz_off(wc * 64 + ni * 16 + lr, lg));
          if (!last_it) stage_half(j2, kt2, kh);
        }

        BAR();
        __builtin_amdgcn_s_setprio(1);
        #pragma unroll
        for (int mi = 0; mi < 4; ++mi)
          #pragma unroll
          for (int ni = 0; ni < 4; ++ni)
            acc[mh * 4 + mi][ni] = __builtin_amdgcn_mfma_f32_16x16x32_bf16(
                af[mi], bfrag[ni], acc[mh * 4 + mi][ni], 0, 0, 0);
        __builtin_amdgcn_s_setprio(0);

        if (ph == 1) {
          if (!last_it) WAIT_VM(4);
          else          WAIT_VM(0);
          BAR();
        } else if (ph == 3) {
          if (!last_it) {
            WAIT_VM(4);
            BAR();
          }
        } else {
          BAR();
        }
      }
    }

    // Epilogue for tile j (static biasr index; registers/stores only).
    {
      int colbase = (ngrp * TPB + j) * BN + wc * 64;
      int rowbase = mblk * BM + wr * 128;
      #pragma unroll
      for (int mh = 0; mh < 2; ++mh)
        #pragma unroll
        for (int mi = 0; mi < 4; ++mi) {
          int row0 = rowbase + mh * 64 + mi * 16 + lg * 4;
          #pragma unroll
          for (int ni = 0; ni < 4; ++ni) {
            int col = colbase + ni * 16 + lr;
            f32x4 cv = acc[mh * 4 + mi][ni];
            #pragma unroll
            for (int jj = 0; jj < 4; ++jj)
              C[(size_t)(row0 + jj) * DOUT + col] = cv[jj] + biasr[j][ni];
          }
        }
      #pragma unroll
      for (int q = 0; q < 8; ++q)
        #pragma unroll
        for (int ni = 0; ni < 4; ++ni)
          acc[q][ni] = (f32x4){0.f, 0.f, 0.f, 0.f};
    }
  }
}

// Correct-but-slow fallback if workspace is too small (should not trigger).
__global__ void venom_naive(const float* __restrict__ x, const float* __restrict__ w,
                            const float* __restrict__ bias, float* __restrict__ out) {
  size_t total = (size_t)MROWS * DOUT;
  size_t stride = (size_t)gridDim.x * blockDim.x;
  for (size_t idx = (size_t)blockIdx.x * blockDim.x + threadIdx.x; idx < total;
       idx += stride) {
    int m = (int)(idx / DOUT), n = (int)(idx % DOUT);
    const float* xr = x + (size_t)m * DIN;
    const float* wr = w + (size_t)n * DIN;
    float s = 0.f;
    for (int g = 0; g < DIN / 8; ++g)
      s += xr[g * 8] * wr[g * 8] + xr[g * 8 + 2] * wr[g * 8 + 2];
    out[idx] = s + bias[n];
  }
}

extern "C" void kernel_launch(void* const* d_in, const int* in_sizes, int n_in,
                              void* d_out, int out_size, void* d_ws, size_t ws_size,
                              hipStream_t stream) {
  const float* x    = (const float*)d_in[0];
  const float* wgt  = (const float*)d_in[1];
  const float* bias = (const float*)d_in[2];
  float* out = (float*)d_out;

  const size_t xg_bytes = (size_t)MROWS * KEFF * 2;  // 33.5 MB
  const size_t wg_bytes = (size_t)DOUT * KEFF * 2;   //  8.4 MB
  const size_t ctr_off  = xg_bytes + wg_bytes;

  if (ws_size < ctr_off + 128) {
    venom_naive<<<2048, 256, 0, stream>>>(x, wgt, bias, out);
    return;
  }

  uint32_t* xg  = (uint32_t*)d_ws;
  uint32_t* wg  = (uint32_t*)((char*)d_ws + xg_bytes);
  uint32_t* ctr = (uint32_t*)((char*)d_ws + ctr_off);

  // Reset the grid-sync counter every launch (graph-capture-safe).
  hipMemsetAsync(ctr, 0, sizeof(uint32_t), stream);

  // 256 blocks = 1 per CU (128 KiB LDS), all co-resident -> spin-sync is safe.
  venom_fused2<<<256, 512, 0, stream>>>(x, wgt, bias, out, xg, wg, ctr);
}